// Round 8
// baseline (331.819 us; speedup 1.0000x reference)
//
#include <hip/hip_runtime.h>
#include <hip/hip_bf16.h>
#include <math.h>

#define B_ 2
#define S_ 2048
#define H_ 4
#define D_ 64
#define W_ 64
#define ST 4                   // s-positions per block (1 per wave)
#define SROW (H_ * D_)         // 256 elements between consecutive s rows
#define VSTR 104               // LDS col stride: 208B = 13 granules, odd -> conflict-free
#define L2T 2144               // v2t row: 64 zero-pad + 2048 + 32 zero-pad
#define QSC 0.18033688011112042f   // (1/sqrt(64)) * log2(e), folded into q

typedef __attribute__((ext_vector_type(8))) short short8;     // 8 bf16 (MFMA A/B frag)
typedef __attribute__((ext_vector_type(4))) float f32x4;      // MFMA C/D frag
typedef __attribute__((ext_vector_type(4))) unsigned short ushort4_t;
typedef __attribute__((ext_vector_type(4))) unsigned int u32x4;

__device__ __forceinline__ unsigned pkbf(float lo, float hi) {  // 2xf32 -> packed bf16
    unsigned r;
    asm("v_cvt_pk_bf16_f32 %0, %1, %2" : "=v"(r) : "v"(lo), "v"(hi));
    return r;
}

__device__ __forceinline__ unsigned short cbf(float f) {
    __hip_bfloat16 h = __float2bfloat16(f);
    unsigned short u;
    __builtin_memcpy(&u, &h, 2);
    return u;
}

// ---- prologue 1: k2 f32 -> bf16 (same layout); proven round 5 ----
__global__ __launch_bounds__(256)
void cvt_k2(const float* __restrict__ in, unsigned short* __restrict__ outp, int n8) {
    int i = blockIdx.x * 256 + threadIdx.x;
    if (i >= n8) return;
    float4 x = ((const float4*)in)[2 * i];
    float4 y = ((const float4*)in)[2 * i + 1];
    u32x4 o = { pkbf(x.x, x.y), pkbf(x.z, x.w), pkbf(y.x, y.y), pkbf(y.z, y.w) };
    *(u32x4*)(outp + 8 * (size_t)i) = o;
}

// ---- prologue 2: v2 -> bf16 transposed [b][h][d][L2T], zero pads both ends ----
// v2t[d][x] = v2[x - 64]; proven rounds 5/7.
__global__ __launch_bounds__(256)
void v2t_kernel(const float* __restrict__ v2, unsigned short* __restrict__ v2t) {
    const int s0 = blockIdx.x * 64;
    const int h = blockIdx.y, b = blockIdx.z;
    const int tid = threadIdx.x;
    __shared__ unsigned short t[64][72];
    const size_t base_bh = (size_t)(b * S_ * H_ + h) * D_;
    const int d = tid & 63;
    for (int i = tid >> 6; i < 64; i += 4)
        t[d][i] = cbf(v2[base_bh + (size_t)(s0 + i) * SROW + d]);
    __syncthreads();
    const size_t obase = ((size_t)(b * H_ + h) * D_) * L2T;
    const short8 z = {0,0,0,0,0,0,0,0};
    for (int idx = tid; idx < 64 * 8; idx += 256) {
        int dd = idx >> 3, c8 = idx & 7;
        *(short8*)(v2t + obase + (size_t)dd * L2T + 64 + s0 + c8 * 8) = *(short8*)&t[dd][c8 * 8];
        if (blockIdx.x == 0)
            *(short8*)(v2t + obase + (size_t)dd * L2T + c8 * 8) = z;           // left pad [0,64)
    }
    if (blockIdx.x == (S_ / 64) - 1) {
        for (int idx = tid; idx < 64 * 4; idx += 256) {
            int dd = idx >> 2, c8 = idx & 3;
            *(short8*)(v2t + obase + (size_t)dd * L2T + 64 + S_ + c8 * 8) = z;  // right pad
        }
    }
}

// ---- main body: round-4 structure exactly (single strip loop, b1+b2 resident,
//      16-row Wst with w-shift + scalar writes), round-5-proven micro-opts.
template<bool EDGE>
__device__ __forceinline__ void tsbody(
    const float* __restrict__ q, const float* __restrict__ k1,
    const unsigned short* __restrict__ k2b, const float* __restrict__ v1,
    float* __restrict__ out,
    const unsigned short (*__restrict__ v2T)[VSTR],
    unsigned short (*Wst)[VSTR],
    int s, int base_bh, int m16, int g4, int w, int lane)
{
    const int amin = (EDGE && s < W_) ? (W_ - s) : 0;

    // q fragment values, pre-scaled by SCALE*log2e
    float qf[16];
    {
        const float* qp = q + base_bh + s * SROW + g4 * 8;
        #pragma unroll
        for (int kk = 0; kk < 2; ++kk) {
            float4 x = *(const float4*)(qp + kk * 32);
            float4 y = *(const float4*)(qp + kk * 32 + 4);
            qf[kk*8+0]=x.x*QSC; qf[kk*8+1]=x.y*QSC; qf[kk*8+2]=x.z*QSC; qf[kk*8+3]=x.w*QSC;
            qf[kk*8+4]=y.x*QSC; qf[kk*8+5]=y.y*QSC; qf[kk*8+6]=y.z*QSC; qf[kk*8+7]=y.w*QSC;
        }
    }

    // zero-fill shift pads: cols [0,w) and [80+w,96) across all 16 rows (round-4 proven)
    #pragma unroll
    for (int r = 0; r < 4; ++r) {
        const int row = g4 * 4 + r;
        if (m16 < w)      Wst[row][m16] = 0;
        if (m16 < 16 - w) Wst[row][80 + w + m16] = 0;
    }

    // B1 = K2^T fragments (direct bf16 loads): lane col c = cm*16+m16, k = kk*32+g4*8..+7
    short8 b1[5][2];
    #pragma unroll
    for (int cm = 0; cm < 5; ++cm) {
        int j = s - W_ + cm * 16 + m16;
        if (EDGE) j = j < 0 ? 0 : (j > S_ - 1 ? S_ - 1 : j);
        const unsigned short* kp = k2b + base_bh + j * SROW + g4 * 8;
        b1[cm][0] = *(const short8*)kp;
        b1[cm][1] = *(const short8*)(kp + 32);
    }

    // B2 = V2 fragments from v2T (block-relative r): lane d = dn*16+m16, r = kk*32+g4*8..+7
    short8 b2[4][3];
    #pragma unroll
    for (int dn = 0; dn < 4; ++dn)
        #pragma unroll
        for (int kk = 0; kk < 3; ++kk)
            b2[dn][kk] = *(const short8*)&v2T[dn * 16 + m16][kk * 32 + g4 * 8];

    float dsum = 0.f;
    float pnum[4] = {0.f, 0.f, 0.f, 0.f};

    #pragma unroll
    for (int strip = 0; strip < 5; ++strip) {
        // A1 = P = q .* k1 (f32 loads, mul, pkbf pack): lane row a = strip*16+m16
        short8 a1[2];
        {
            const float* kp;
            if (EDGE) {
                int j = s - W_ + strip * 16 + m16;
                j = j < 0 ? 0 : (j > S_ - 1 ? S_ - 1 : j);
                kp = k1 + base_bh + j * SROW + g4 * 8;
            } else {
                kp = k1 + base_bh + (s - W_ + strip * 16 + m16) * SROW + g4 * 8;
            }
            #pragma unroll
            for (int kk = 0; kk < 2; ++kk) {
                float4 x = *(const float4*)(kp + kk * 32);
                float4 y = *(const float4*)(kp + kk * 32 + 4);
                u32x4 o = { pkbf(x.x * qf[kk*8+0], x.y * qf[kk*8+1]),
                            pkbf(x.z * qf[kk*8+2], x.w * qf[kk*8+3]),
                            pkbf(y.x * qf[kk*8+4], y.y * qf[kk*8+5]),
                            pkbf(y.z * qf[kk*8+6], y.w * qf[kk*8+7]) };
                a1[kk] = *(short8*)&o;
            }
        }

        // scores: D[m=a][n=c] (round-4 orientation)
        f32x4 acc1[5];
        #pragma unroll
        for (int cm = 0; cm < 5; ++cm) {
            acc1[cm] = (f32x4){0.f, 0.f, 0.f, 0.f};
            acc1[cm] = __builtin_amdgcn_mfma_f32_16x16x32_bf16(a1[0], b1[cm][0], acc1[cm], 0, 0, 0);
            acc1[cm] = __builtin_amdgcn_mfma_f32_16x16x32_bf16(a1[1], b1[cm][1], acc1[cm], 0, 0, 0);
        }

        // exp + mask -> Wst rows a_local = g4*4+r, col c+w (scalar b16, round-4 proven)
        #pragma unroll
        for (int cm = 0; cm < 5; ++cm) {
            const int c = cm * 16 + m16;
            const bool cok = EDGE ? (c >= amin && c <= W_) : (c <= W_);
            #pragma unroll
            for (int r = 0; r < 4; ++r) {
                const int a = strip * 16 + g4 * 4 + r;
                const bool ok = cok && (a <= W_) && (!EDGE || a >= amin);
                const float wv = ok ? __builtin_amdgcn_exp2f(acc1[cm][r]) : 0.f;
                dsum += wv;
                Wst[g4 * 4 + r][c + w] = cbf(wv);
            }
        }

        // phase 2: U[a][d] = sum_r W'[a][r] * v2T[r][d], K = 96
        short8 a2[3];
        #pragma unroll
        for (int kk = 0; kk < 3; ++kk)
            a2[kk] = *(const short8*)&Wst[m16][kk * 32 + g4 * 8];

        const float* v1s = v1 + base_bh + (s - W_ + strip * 16 + g4 * 4) * SROW + m16;

        #pragma unroll
        for (int dn = 0; dn < 4; ++dn) {
            f32x4 acc2 = (f32x4){0.f, 0.f, 0.f, 0.f};
            #pragma unroll
            for (int kk = 0; kk < 3; ++kk)
                acc2 = __builtin_amdgcn_mfma_f32_16x16x32_bf16(a2[kk], b2[dn][kk], acc2, 0, 0, 0);
            #pragma unroll
            for (int r = 0; r < 4; ++r) {
                float v1v;
                if (EDGE) {
                    int j = s - W_ + strip * 16 + g4 * 4 + r;
                    j = j < 0 ? 0 : (j > S_ - 1 ? S_ - 1 : j);
                    v1v = v1[base_bh + j * SROW + dn * 16 + m16];
                } else {
                    v1v = v1s[r * SROW + dn * 16];   // imm-foldable offsets
                }
                pnum[dn] += acc2[r] * v1v;   // invalid rows: acc2 == 0
            }
        }
    }

    #pragma unroll
    for (int off = 32; off >= 1; off >>= 1) dsum += __shfl_xor(dsum, off, 64);
    #pragma unroll
    for (int dn = 0; dn < 4; ++dn) {
        pnum[dn] += __shfl_xor(pnum[dn], 16, 64);
        pnum[dn] += __shfl_xor(pnum[dn], 32, 64);
    }
    if (lane < 16) {
        const float inv = 1.f / (dsum + 1e-8f);
        #pragma unroll
        for (int dn = 0; dn < 4; ++dn)
            out[base_bh + s * SROW + dn * 16 + lane] = pnum[dn] * inv;
    }
}

__global__ __launch_bounds__(256, 3)
void tsattn_mfma(const float* __restrict__ q, const float* __restrict__ k1,
                 const unsigned short* __restrict__ k2b, const float* __restrict__ v1,
                 const unsigned short* __restrict__ v2t, float* __restrict__ out)
{
    __shared__ unsigned short v2T[D_][VSTR];        // 13,312 B, block-shared
    __shared__ unsigned short Wst[ST][16][VSTR];    // 13,312 B, per-wave strips
    const int s0 = blockIdx.x * ST;
    const int h = blockIdx.y, b = blockIdx.z;
    const int tid = threadIdx.x, lane = tid & 63, w = tid >> 6;
    const int m16 = lane & 15, g4 = lane >> 4;
    const int s = s0 + w;
    const int base_bh = b * S_ * SROW + h * D_;

    // stage v2T[d][r] = v2[s0 - 64 + r][d] (bf16), r in [0,96); pads give zeros (round-4 proven)
    {
        const unsigned short* src = v2t + (size_t)((b * H_ + h) * D_) * L2T + s0;
        for (int idx = tid; idx < 64 * 24; idx += 256) {
            int d = idx / 24, rc = idx % 24;
            *(ushort4_t*)&v2T[d][rc * 4] = *(const ushort4_t*)(src + (size_t)d * L2T + rc * 4);
        }
    }
    __syncthreads();

    const bool edge = (s0 < W_) || (s0 + 18 > S_ - 1);
    if (edge)
        tsbody<true >(q, k1, k2b, v1, out, v2T, Wst[w], s, base_bh, m16, g4, w, lane);
    else
        tsbody<false>(q, k1, k2b, v1, out, v2T, Wst[w], s, base_bh, m16, g4, w, lane);
}

extern "C" void kernel_launch(void* const* d_in, const int* in_sizes, int n_in,
                              void* d_out, int out_size, void* d_ws, size_t ws_size,
                              hipStream_t stream) {
    const float* q  = (const float*)d_in[0];
    const float* k1 = (const float*)d_in[1];
    const float* k2 = (const float*)d_in[2];
    const float* v1 = (const float*)d_in[3];
    const float* v2 = (const float*)d_in[4];
    float* out = (float*)d_out;

    const size_t NE = (size_t)B_ * S_ * H_ * D_;   // 1,048,576
    unsigned short* k2b = (unsigned short*)d_ws;   // 2 MB
    unsigned short* v2t = k2b + NE;                // B*H*D*L2T ushorts = 2.2 MB (total 4.3 MB)

    const int n8 = (int)(NE / 8);
    cvt_k2<<<(n8 + 255) / 256, 256, 0, stream>>>(k2, k2b, n8);
    v2t_kernel<<<dim3(S_ / 64, H_, B_), 256, 0, stream>>>(v2, v2t);

    tsattn_mfma<<<dim3(S_ / ST, H_, B_), 256, 0, stream>>>(q, k1, k2b, v1, v2t, out);
}

// Round 9
// 309.189 us; speedup vs baseline: 1.0732x; 1.0732x over previous
//
#include <hip/hip_runtime.h>
#include <hip/hip_bf16.h>
#include <math.h>

#define B_ 2
#define S_ 2048
#define H_ 4
#define D_ 64
#define W_ 64
#define ST 4                   // s-positions per block (1 per wave)
#define SROW (H_ * D_)         // 256 elements between consecutive s rows
#define VSTR 104               // LDS col stride: 208B = 13 granules, odd -> conflict-free
#define L2T 2144               // v2t row: 64 zero-pad + 2048 + 32 zero-pad
#define QSC 0.18033688011112042f   // (1/sqrt(64)) * log2(e), folded into q

typedef __attribute__((ext_vector_type(8))) short short8;     // 8 bf16 (MFMA A/B frag)
typedef __attribute__((ext_vector_type(4))) float f32x4;      // MFMA C/D frag
typedef __attribute__((ext_vector_type(4))) unsigned short ushort4_t;
typedef __attribute__((ext_vector_type(4))) unsigned int u32x4;

__device__ __forceinline__ unsigned pkbf(float lo, float hi) {  // 2xf32 -> packed bf16
    unsigned r;
    asm("v_cvt_pk_bf16_f32 %0, %1, %2" : "=v"(r) : "v"(lo), "v"(hi));
    return r;
}

__device__ __forceinline__ unsigned short cbf(float f) {
    __hip_bfloat16 h = __float2bfloat16(f);
    unsigned short u;
    __builtin_memcpy(&u, &h, 2);
    return u;
}

// ---- prologue 1: bulk f32 -> bf16 for k1, k2 (same layout); round-4 proven ----
__global__ __launch_bounds__(256)
void cvt2_kernel(const float* __restrict__ a, const float* __restrict__ b,
                 unsigned short* __restrict__ oa, unsigned short* __restrict__ ob, int n8) {
    int i = blockIdx.x * 256 + threadIdx.x;
    if (i >= 2 * n8) return;
    const float* s = (i < n8) ? a : b;
    unsigned short* d = (i < n8) ? oa : ob;
    int k = (i < n8) ? i : i - n8;
    float4 x = ((const float4*)s)[2 * k];
    float4 y = ((const float4*)s)[2 * k + 1];
    u32x4 o = { pkbf(x.x, x.y), pkbf(x.z, x.w), pkbf(y.x, y.y), pkbf(y.z, y.w) };
    *(u32x4*)(d + 8 * (size_t)k) = o;
}

// ---- prologue 2: v2 -> bf16 transposed [b][h][d][L2T], zero pads both ends ----
// v2t[d][x] = v2[x - 64]; proven rounds 5/8.
__global__ __launch_bounds__(256)
void v2t_kernel(const float* __restrict__ v2, unsigned short* __restrict__ v2t) {
    const int s0 = blockIdx.x * 64;
    const int h = blockIdx.y, b = blockIdx.z;
    const int tid = threadIdx.x;
    __shared__ unsigned short t[64][72];
    const size_t base_bh = (size_t)(b * S_ * H_ + h) * D_;
    const int d = tid & 63;
    for (int i = tid >> 6; i < 64; i += 4)
        t[d][i] = cbf(v2[base_bh + (size_t)(s0 + i) * SROW + d]);
    __syncthreads();
    const size_t obase = ((size_t)(b * H_ + h) * D_) * L2T;
    const short8 z = {0,0,0,0,0,0,0,0};
    for (int idx = tid; idx < 64 * 8; idx += 256) {
        int dd = idx >> 3, c8 = idx & 7;
        *(short8*)(v2t + obase + (size_t)dd * L2T + 64 + s0 + c8 * 8) = *(short8*)&t[dd][c8 * 8];
        if (blockIdx.x == 0)
            *(short8*)(v2t + obase + (size_t)dd * L2T + c8 * 8) = z;           // left pad [0,64)
    }
    if (blockIdx.x == (S_ / 64) - 1) {
        for (int idx = tid; idx < 64 * 4; idx += 256) {
            int dd = idx >> 2, c8 = idx & 3;
            *(short8*)(v2t + obase + (size_t)dd * L2T + 64 + S_ + c8 * 8) = z;  // right pad
        }
    }
}

// ---- main body: round-4 structure (single strip loop, b1+b2 resident, bf16 k1b
//      a1 path -> low load footprint, no spills) + round-8 micro-opts.
template<bool EDGE>
__device__ __forceinline__ void tsbody(
    const float* __restrict__ q, const unsigned short* __restrict__ k1b,
    const unsigned short* __restrict__ k2b, const float* __restrict__ v1,
    float* __restrict__ out,
    const unsigned short (*__restrict__ v2T)[VSTR],
    unsigned short (*Wst)[VSTR],
    int s, int base_bh, int m16, int g4, int w, int lane)
{
    const int amin = (EDGE && s < W_) ? (W_ - s) : 0;

    // q fragment values, pre-scaled by SCALE*log2e
    float qf[16];
    {
        const float* qp = q + base_bh + s * SROW + g4 * 8;
        #pragma unroll
        for (int kk = 0; kk < 2; ++kk) {
            float4 x = *(const float4*)(qp + kk * 32);
            float4 y = *(const float4*)(qp + kk * 32 + 4);
            qf[kk*8+0]=x.x*QSC; qf[kk*8+1]=x.y*QSC; qf[kk*8+2]=x.z*QSC; qf[kk*8+3]=x.w*QSC;
            qf[kk*8+4]=y.x*QSC; qf[kk*8+5]=y.y*QSC; qf[kk*8+6]=y.z*QSC; qf[kk*8+7]=y.w*QSC;
        }
    }

    // zero-fill shift pads: cols [0,w) and [80+w,96) across all 16 rows (round-4 proven)
    #pragma unroll
    for (int r = 0; r < 4; ++r) {
        const int row = g4 * 4 + r;
        if (m16 < w)      Wst[row][m16] = 0;
        if (m16 < 16 - w) Wst[row][80 + w + m16] = 0;
    }

    // B1 = K2^T fragments (direct bf16 loads): lane col c = cm*16+m16, k = kk*32+g4*8..+7
    short8 b1[5][2];
    #pragma unroll
    for (int cm = 0; cm < 5; ++cm) {
        int j = s - W_ + cm * 16 + m16;
        if (EDGE) j = j < 0 ? 0 : (j > S_ - 1 ? S_ - 1 : j);
        const unsigned short* kp = k2b + base_bh + j * SROW + g4 * 8;
        b1[cm][0] = *(const short8*)kp;
        b1[cm][1] = *(const short8*)(kp + 32);
    }

    // B2 = V2 fragments from v2T (block-relative r): lane d = dn*16+m16, r = kk*32+g4*8..+7
    short8 b2[4][3];
    #pragma unroll
    for (int dn = 0; dn < 4; ++dn)
        #pragma unroll
        for (int kk = 0; kk < 3; ++kk)
            b2[dn][kk] = *(const short8*)&v2T[dn * 16 + m16][kk * 32 + g4 * 8];

    float dsum = 0.f;
    float pnum[4] = {0.f, 0.f, 0.f, 0.f};

    #pragma unroll
    for (int strip = 0; strip < 5; ++strip) {
        // A1 = P = q .* k1 from bf16 k1b: 2 short8 loads, dword unpack + mul + pkbf
        short8 a1[2];
        {
            int j = s - W_ + strip * 16 + m16;
            if (EDGE) j = j < 0 ? 0 : (j > S_ - 1 ? S_ - 1 : j);
            const unsigned short* kp = k1b + base_bh + j * SROW + g4 * 8;
            #pragma unroll
            for (int kk = 0; kk < 2; ++kk) {
                u32x4 kv = *(const u32x4*)(kp + kk * 32);
                u32x4 o;
                #pragma unroll
                for (int i = 0; i < 4; ++i) {
                    const float lo = __uint_as_float(kv[i] << 16);          // elem 2i
                    const float hi = __uint_as_float(kv[i] & 0xffff0000u);  // elem 2i+1
                    o[i] = pkbf(lo * qf[kk*8 + 2*i], hi * qf[kk*8 + 2*i + 1]);
                }
                a1[kk] = *(short8*)&o;
            }
        }

        // scores: D[m=a][n=c]
        f32x4 acc1[5];
        #pragma unroll
        for (int cm = 0; cm < 5; ++cm) {
            acc1[cm] = (f32x4){0.f, 0.f, 0.f, 0.f};
            acc1[cm] = __builtin_amdgcn_mfma_f32_16x16x32_bf16(a1[0], b1[cm][0], acc1[cm], 0, 0, 0);
            acc1[cm] = __builtin_amdgcn_mfma_f32_16x16x32_bf16(a1[1], b1[cm][1], acc1[cm], 0, 0, 0);
        }

        // exp + mask -> Wst rows a_local = g4*4+r, col c+w (scalar b16, round-4 proven)
        #pragma unroll
        for (int cm = 0; cm < 5; ++cm) {
            const int c = cm * 16 + m16;
            const bool cok = EDGE ? (c >= amin && c <= W_) : (c <= W_);
            #pragma unroll
            for (int r = 0; r < 4; ++r) {
                const int a = strip * 16 + g4 * 4 + r;
                const bool ok = cok && (a <= W_) && (!EDGE || a >= amin);
                const float wv = ok ? __builtin_amdgcn_exp2f(acc1[cm][r]) : 0.f;
                dsum += wv;
                Wst[g4 * 4 + r][c + w] = cbf(wv);
            }
        }

        // phase 2: U[a][d] = sum_r W'[a][r] * v2T[r][d], K = 96
        short8 a2[3];
        #pragma unroll
        for (int kk = 0; kk < 3; ++kk)
            a2[kk] = *(const short8*)&Wst[m16][kk * 32 + g4 * 8];

        const float* v1s = v1 + base_bh + (s - W_ + strip * 16 + g4 * 4) * SROW + m16;

        #pragma unroll
        for (int dn = 0; dn < 4; ++dn) {
            f32x4 acc2 = (f32x4){0.f, 0.f, 0.f, 0.f};
            #pragma unroll
            for (int kk = 0; kk < 3; ++kk)
                acc2 = __builtin_amdgcn_mfma_f32_16x16x32_bf16(a2[kk], b2[dn][kk], acc2, 0, 0, 0);
            #pragma unroll
            for (int r = 0; r < 4; ++r) {
                float v1v;
                if (EDGE) {
                    int j = s - W_ + strip * 16 + g4 * 4 + r;
                    j = j < 0 ? 0 : (j > S_ - 1 ? S_ - 1 : j);
                    v1v = v1[base_bh + j * SROW + dn * 16 + m16];
                } else {
                    v1v = v1s[r * SROW + dn * 16];   // imm-foldable offsets
                }
                pnum[dn] += acc2[r] * v1v;   // invalid rows: acc2 == 0
            }
        }
    }

    #pragma unroll
    for (int off = 32; off >= 1; off >>= 1) dsum += __shfl_xor(dsum, off, 64);
    #pragma unroll
    for (int dn = 0; dn < 4; ++dn) {
        pnum[dn] += __shfl_xor(pnum[dn], 16, 64);
        pnum[dn] += __shfl_xor(pnum[dn], 32, 64);
    }
    if (lane < 16) {
        const float inv = 1.f / (dsum + 1e-8f);
        #pragma unroll
        for (int dn = 0; dn < 4; ++dn)
            out[base_bh + s * SROW + dn * 16 + lane] = pnum[dn] * inv;
    }
}

__global__ __launch_bounds__(256, 3)
void tsattn_mfma(const float* __restrict__ q, const unsigned short* __restrict__ k1b,
                 const unsigned short* __restrict__ k2b, const float* __restrict__ v1,
                 const unsigned short* __restrict__ v2t, float* __restrict__ out)
{
    __shared__ unsigned short v2T[D_][VSTR];        // 13,312 B, block-shared
    __shared__ unsigned short Wst[ST][16][VSTR];    // 13,312 B, per-wave strips
    const int s0 = blockIdx.x * ST;
    const int h = blockIdx.y, b = blockIdx.z;
    const int tid = threadIdx.x, lane = tid & 63, w = tid >> 6;
    const int m16 = lane & 15, g4 = lane >> 4;
    const int s = s0 + w;
    const int base_bh = b * S_ * SROW + h * D_;

    // stage v2T[d][r] = v2[s0 - 64 + r][d] (bf16), r in [0,96); pads give zeros
    {
        const unsigned short* src = v2t + (size_t)((b * H_ + h) * D_) * L2T + s0;
        for (int idx = tid; idx < 64 * 24; idx += 256) {
            int d = idx / 24, rc = idx % 24;
            *(ushort4_t*)&v2T[d][rc * 4] = *(const ushort4_t*)(src + (size_t)d * L2T + rc * 4);
        }
    }
    __syncthreads();

    const bool edge = (s0 < W_) || (s0 + 18 > S_ - 1);
    if (edge)
        tsbody<true >(q, k1b, k2b, v1, out, v2T, Wst[w], s, base_bh, m16, g4, w, lane);
    else
        tsbody<false>(q, k1b, k2b, v1, out, v2T, Wst[w], s, base_bh, m16, g4, w, lane);
}

extern "C" void kernel_launch(void* const* d_in, const int* in_sizes, int n_in,
                              void* d_out, int out_size, void* d_ws, size_t ws_size,
                              hipStream_t stream) {
    const float* q  = (const float*)d_in[0];
    const float* k1 = (const float*)d_in[1];
    const float* k2 = (const float*)d_in[2];
    const float* v1 = (const float*)d_in[3];
    const float* v2 = (const float*)d_in[4];
    float* out = (float*)d_out;

    const size_t NE = (size_t)B_ * S_ * H_ * D_;   // 1,048,576
    unsigned short* k1b = (unsigned short*)d_ws;   // 2 MB
    unsigned short* k2b = k1b + NE;                // 2 MB
    unsigned short* v2t = k2b + NE;                // B*H*D*L2T ushorts = 2.2 MB (total 6.2 MB)

    const int n8 = (int)(NE / 8);
    cvt2_kernel<<<(2 * n8 + 255) / 256, 256, 0, stream>>>(k1, k2, k1b, k2b, n8);
    v2t_kernel<<<dim3(S_ / 64, H_, B_), 256, 0, stream>>>(v2, v2t);

    tsattn_mfma<<<dim3(S_ / ST, H_, B_), 256, 0, stream>>>(q, k1b, k2b, v1, v2t, out);
}